// Round 3
// baseline (244.250 us; speedup 1.0000x reference)
//
#include <hip/hip_runtime.h>

#define B_    2
#define T_    2048
#define C_    1024
#define H_    16
#define DH_   64
#define M_    (B_ * T_)        // 4096 tokens
#define NQKV  (3 * C_)         // 3072

typedef __bf16 bf16;
typedef __bf16 bf16x4 __attribute__((ext_vector_type(4)));
typedef __bf16 bf16x8 __attribute__((ext_vector_type(8)));
typedef float  f32x4  __attribute__((ext_vector_type(4)));

// async global->LDS, 16B per lane (global_load_lds_dwordx4).
// LDS dest must be wave-uniform base + lane*16 (no per-lane scatter).
__device__ __forceinline__ void async16(const void* g, void* l) {
  __builtin_amdgcn_global_load_lds(
      (const __attribute__((address_space(1))) void*)g,
      (__attribute__((address_space(3))) void*)l, 16, 0, 0);
}

// ---------------------------------------------------------------- converts
__global__ __launch_bounds__(256) void cvt_bf16_k(const float* __restrict__ in,
                                                  bf16* __restrict__ out) {
  const int i = (blockIdx.x * 256 + threadIdx.x) * 4;
  float4 v = *(const float4*)(in + i);
  bf16x4 o;
  o[0] = (bf16)v.x; o[1] = (bf16)v.y; o[2] = (bf16)v.z; o[3] = (bf16)v.w;
  *(bf16x4*)(out + i) = o;
}

// in: fp32 [R x C] row-major; out: bf16 [C x R] (i.e. transposed), both coalesced
__global__ __launch_bounds__(256) void transpose_cvt(const float* __restrict__ in,
                                                     bf16* __restrict__ out,
                                                     int R, int C) {
  __shared__ float tile[32][33];
  const int c0 = blockIdx.x * 32, r0 = blockIdx.y * 32;
  const int tx = threadIdx.x, ty = threadIdx.y;
#pragma unroll
  for (int j = 0; j < 4; j++)
    tile[ty + j * 8][tx] = in[(size_t)(r0 + ty + j * 8) * C + c0 + tx];
  __syncthreads();
#pragma unroll
  for (int j = 0; j < 4; j++)
    out[(size_t)(c0 + ty + j * 8) * R + r0 + tx] = (bf16)tile[tx][ty + j * 8];
}

// ---------------------------------------------------------------- GEMM
// C[M,N] = A[M,K=1024] * Bt[N,K]^T (+bias). 128x128 tile, BK=32, 4 waves.
// Pipelined: barrier -> issue prefetch(i+1) into other LDS buffer -> compute(i).
// The barrier's vmcnt(0) drains only L(i) (which overlapped compute(i-1));
// L(i+1) stays in flight through compute(i). One barrier per iter.
// LDS column-groups XOR-swizzled by (row>>1)&3 (kills 8-way b128 conflict).
template <int EPI>
__global__ __launch_bounds__(256) void gemm128(
    const bf16* __restrict__ A, const bf16* __restrict__ Bt,
    const float* __restrict__ bias, float* __restrict__ outF,
    bf16* __restrict__ qb, bf16* __restrict__ kb, bf16* __restrict__ vtb) {
  constexpr int K = 1024;
  __shared__ alignas(16) bf16 As[2][128 * 32];
  __shared__ alignas(16) bf16 Bs[2][128 * 32];
  const int tid = threadIdx.x;
  const int lane = tid & 63, wv = tid >> 6;
  const int l15 = lane & 15, quad = lane >> 4;
  const int wm = (wv >> 1) * 64, wn = (wv & 1) * 64;
  const int m0 = blockIdx.x * 128, n0 = blockIdx.y * 128;

  f32x4 acc[4][4] = {};

  const int arow = tid >> 2;                       // 0..63 (and +64)
  const int ag = (tid & 3) ^ ((arow >> 1) & 3);    // swizzled col group
  const bf16* ga = A + (size_t)(m0 + arow) * K + ag * 8;
  const bf16* gb = Bt + (size_t)(n0 + arow) * K + ag * 8;
  const int rg = (quad ^ ((l15 >> 1) & 3)) * 8;    // read-side swizzled group

  // prologue: stage k-tile 0 into buffer 0
  async16(ga, &As[0][tid * 8]);
  async16(ga + (size_t)64 * K, &As[0][tid * 8 + 2048]);
  async16(gb, &Bs[0][tid * 8]);
  async16(gb + (size_t)64 * K, &Bs[0][tid * 8 + 2048]);

  for (int it = 0; it < K / 32; ++it) {
    __syncthreads();                               // waits L(it), joins waves
    if (it + 1 < K / 32) {                         // prefetch L(it+1)
      const int k1 = (it + 1) * 32;
      const int nb = (it + 1) & 1;
      async16(ga + k1, &As[nb][tid * 8]);
      async16(ga + k1 + (size_t)64 * K, &As[nb][tid * 8 + 2048]);
      async16(gb + k1, &Bs[nb][tid * 8]);
      async16(gb + k1 + (size_t)64 * K, &Bs[nb][tid * 8 + 2048]);
    }
    const bf16* Ac = As[it & 1];
    const bf16* Bc = Bs[it & 1];
    bf16x8 af[4], bfr[4];
#pragma unroll
    for (int i = 0; i < 4; i++)
      af[i] = *(const bf16x8*)(Ac + (wm + i * 16 + l15) * 32 + rg);
#pragma unroll
    for (int j = 0; j < 4; j++)
      bfr[j] = *(const bf16x8*)(Bc + (wn + j * 16 + l15) * 32 + rg);
#pragma unroll
    for (int i = 0; i < 4; i++)
#pragma unroll
      for (int j = 0; j < 4; j++)
        acc[i][j] = __builtin_amdgcn_mfma_f32_16x16x32_bf16(af[i], bfr[j],
                                                            acc[i][j], 0, 0, 0);
  }

  // epilogue: C/D layout col=lane&15, row=quad*4+reg
#pragma unroll
  for (int i = 0; i < 4; i++) {
#pragma unroll
    for (int j = 0; j < 4; j++) {
      const int gcol = n0 + wn + j * 16 + l15;
      const float bv = bias[gcol];
#pragma unroll
      for (int r = 0; r < 4; r++) {
        const int grow = m0 + wm + i * 16 + quad * 4 + r;
        float v = acc[i][j][r] + bv;
        if constexpr (EPI == 0) {
          const int which = gcol >> 10;          // 0=Q 1=K 2=V
          const int hn = gcol & 1023;
          const int h = hn >> 6, d = hn & 63;
          const int bb = grow >> 11, t = grow & 2047;
          const int head = bb * 16 + h;          // 0..31
          if (which == 0)
            qb[head * 131072 + t * 64 + d] = (bf16)(v * 0.1803368801f); // 1/8 * log2(e)
          else if (which == 1)
            kb[head * 131072 + t * 64 + d] = (bf16)v;
          else
            vtb[head * 131072 + d * 2048 + t] = (bf16)v;
        } else {
          outF[(size_t)grow * 1024 + gcol] = v;
        }
      }
    }
  }
}

// ---------------------------------------------------------------- flash attention
// 1D grid of 1024 blocks; qi interleaved heavy/light so round-robin CU
// assignment gives every CU ~66 tile-iters. 4 waves; wave w owns q rows
// [q0+16w,+16). Double-buffered K/V with post-barrier prefetch (see gemm128).
// K/V LDS groups XOR-swizzled by row&7; P per-wave, stride 64 + XOR swizzle.
// Row-sum l maintained by MFMA against an all-ones B fragment (no shfl reduce).
__global__ __launch_bounds__(256) void attn_k(const bf16* __restrict__ Q,
                                              const bf16* __restrict__ K,
                                              const bf16* __restrict__ Vt,
                                              bf16* __restrict__ O) {
  __shared__ alignas(16) bf16 Ks[2][64 * 64];    // [kt][d], swizzled
  __shared__ alignas(16) bf16 Vs[2][64 * 64];    // [d][kt], swizzled
  __shared__ alignas(16) bf16 Ps[4 * 16 * 64];   // per-wave P, swizzled
  const int tid = threadIdx.x, lane = tid & 63, wv = tid >> 6;
  const int l15 = lane & 15, quad = lane >> 4;

  const int l = blockIdx.x;
  const int x = l & 31;
  const int qi = ((l >> 8) & 1) ? (31 - x) : x;  // heavy/light pairing
  const int bh = (l >> 5) & 31;
  const int q0 = qi * 64;
  const int nIter = qi + 1;

  const bf16* Qb = Q + (size_t)bh * 131072;
  const bf16* Kb = K + (size_t)bh * 131072;
  const bf16* Vb = Vt + (size_t)bh * 131072;

  // A-operand: A[m=lane&15][k=quad*8+j]
  const int qrow = q0 + wv * 16 + l15;
  bf16x8 aq0 = *(const bf16x8*)(Qb + qrow * 64 + quad * 8);
  bf16x8 aq1 = *(const bf16x8*)(Qb + qrow * 64 + 32 + quad * 8);

  bf16x8 ones;
#pragma unroll
  for (int j = 0; j < 8; j++) ones[j] = (bf16)1.0f;

  f32x4 o[4] = {};
  f32x4 o_l = {};                                // row-sum accumulator (P * 1)
  float mrow[4] = {-3.0e38f, -3.0e38f, -3.0e38f, -3.0e38f};

  const int srow = tid >> 3;                     // 0..31 (and +32)
  const int sg = (tid & 7) ^ (srow & 7);         // swizzled col group (global side)
  const bf16* gk = Kb + srow * 64 + sg * 8;
  const bf16* gv = Vb + srow * 2048 + sg * 8;
  bf16* Pw = Ps + wv * 1024;
  const int qbase = q0 + wv * 16 + quad * 4;
  const int swz = l15 & 7;                       // read-side row swizzle key

  // prologue: stage kt-tile 0 into buffer 0
  async16(gk, &Ks[0][tid * 8]);
  async16(gk + 32 * 64, &Ks[0][tid * 8 + 2048]);
  async16(gv, &Vs[0][tid * 8]);
  async16(gv + 32 * 2048, &Vs[0][tid * 8 + 2048]);

  for (int it = 0; it < nIter; ++it) {
    __syncthreads();                             // waits L(it), joins waves
    if (it + 1 < nIter) {                        // prefetch L(it+1)
      const int kt1 = (it + 1) * 64;
      const int nb = (it + 1) & 1;
      async16(gk + kt1 * 64, &Ks[nb][tid * 8]);
      async16(gk + kt1 * 64 + 32 * 64, &Ks[nb][tid * 8 + 2048]);
      async16(gv + kt1, &Vs[nb][tid * 8]);
      async16(gv + kt1 + 32 * 2048, &Vs[nb][tid * 8 + 2048]);
    }
    const bf16* Kc = Ks[it & 1];
    const bf16* Vc = Vs[it & 1];

    // S = Q K^T  (16 x 64), 2 k-chunks x 4 n-frags
    f32x4 s[4] = {};
#pragma unroll
    for (int kc = 0; kc < 2; kc++) {
      bf16x8 a = kc ? aq1 : aq0;
#pragma unroll
      for (int nf = 0; nf < 4; nf++) {
        bf16x8 bk = *(const bf16x8*)(Kc + (nf * 16 + l15) * 64 +
                                     (((kc * 4 + quad) ^ swz) * 8));
        s[nf] = __builtin_amdgcn_mfma_f32_16x16x32_bf16(a, bk, s[nf], 0, 0, 0);
      }
    }

    const bool diag = (it == nIter - 1);  // only diagonal tile needs masking
#pragma unroll
    for (int r = 0; r < 4; r++) {
      const int q = qbase + r;
      const int prow = quad * 4 + r;
      float mx = -3.0e38f;
#pragma unroll
      for (int nf = 0; nf < 4; nf++) {
        float v = s[nf][r];
        if (diag) {
          const int kt = q0 + nf * 16 + l15;
          v = (kt <= q) ? v : -3.0e38f;
          s[nf][r] = v;
        }
        mx = fmaxf(mx, v);
      }
      mx = fmaxf(mx, __shfl_xor(mx, 1));
      mx = fmaxf(mx, __shfl_xor(mx, 2));
      mx = fmaxf(mx, __shfl_xor(mx, 4));
      mx = fmaxf(mx, __shfl_xor(mx, 8));
      const float mnew = fmaxf(mrow[r], mx);
      const float alpha = __builtin_amdgcn_exp2f(mrow[r] - mnew);
      mrow[r] = mnew;
#pragma unroll
      for (int nf = 0; nf < 4; nf++) {
        const float pv = __builtin_amdgcn_exp2f(s[nf][r] - mnew);
        // phys col group = (logical group) ^ (row & 7)
        Pw[prow * 64 + ((((nf << 1) | (l15 >> 3)) ^ (prow & 7)) << 3) + (l15 & 7)] =
            (bf16)pv;
      }
      o_l[r] *= alpha;
#pragma unroll
      for (int nf = 0; nf < 4; nf++) o[nf][r] *= alpha;
    }
    // no barrier: Pw is per-wave (same-wave DS ordering suffices)

    // O += P V : A-frags from Pw (swizzled), B-frags from Vs ([d][kt])
    bf16x8 pa0 = *(const bf16x8*)(Pw + l15 * 64 + ((quad ^ swz) << 3));
    bf16x8 pa1 = *(const bf16x8*)(Pw + l15 * 64 + (((4 + quad) ^ swz) << 3));
    o_l = __builtin_amdgcn_mfma_f32_16x16x32_bf16(pa0, ones, o_l, 0, 0, 0);
    o_l = __builtin_amdgcn_mfma_f32_16x16x32_bf16(pa1, ones, o_l, 0, 0, 0);
#pragma unroll
    for (int kc = 0; kc < 2; kc++) {
      bf16x8 pa = kc ? pa1 : pa0;
#pragma unroll
      for (int nf = 0; nf < 4; nf++) {
        bf16x8 bv = *(const bf16x8*)(Vc + (nf * 16 + l15) * 64 +
                                     (((kc * 4 + quad) ^ swz) * 8));
        o[nf] = __builtin_amdgcn_mfma_f32_16x16x32_bf16(pa, bv, o[nf], 0, 0, 0);
      }
    }
  }

  // epilogue: O[b, t, h*64+d] bf16, normalized by MFMA-maintained row sum
  const int bb = bh >> 4, h = bh & 15;
#pragma unroll
  for (int r = 0; r < 4; r++) {
    const float inv = 1.0f / o_l[r];
    const int q = qbase + r;
#pragma unroll
    for (int nf = 0; nf < 4; nf++)
      O[(size_t)(bb * 2048 + q) * 1024 + h * 64 + nf * 16 + l15] =
          (bf16)(o[nf][r] * inv);
  }
}

// ---------------------------------------------------------------- launch
extern "C" void kernel_launch(void* const* d_in, const int* in_sizes, int n_in,
                              void* d_out, int out_size, void* d_ws, size_t ws_size,
                              hipStream_t stream) {
  const float* x     = (const float*)d_in[0];
  const float* Wqkv  = (const float*)d_in[1];
  const float* bqkv  = (const float*)d_in[2];
  const float* Wproj = (const float*)d_in[3];
  const float* bproj = (const float*)d_in[4];
  float* out = (float*)d_out;

  char* p = (char*)d_ws;
  bf16* xbf    = (bf16*)p; p += (size_t)M_ * C_ * 2;     // 8 MB
  bf16* wqkvT  = (bf16*)p; p += (size_t)NQKV * C_ * 2;   // 6 MB
  bf16* wprojT = (bf16*)p; p += (size_t)C_ * C_ * 2;     // 2 MB
  bf16* Qb     = (bf16*)p; p += (size_t)M_ * C_ * 2;     // 8 MB
  bf16* Kb     = (bf16*)p; p += (size_t)M_ * C_ * 2;     // 8 MB
  bf16* Vtb    = (bf16*)p; p += (size_t)M_ * C_ * 2;     // 8 MB
  bf16* AO     = (bf16*)p;                               // 8 MB (total 48 MB)

  cvt_bf16_k<<<M_ * C_ / 1024, 256, 0, stream>>>(x, xbf);
  transpose_cvt<<<dim3(NQKV / 32, C_ / 32), dim3(32, 8), 0, stream>>>(Wqkv, wqkvT, C_, NQKV);
  transpose_cvt<<<dim3(C_ / 32, C_ / 32), dim3(32, 8), 0, stream>>>(Wproj, wprojT, C_, C_);

  gemm128<0><<<dim3(M_ / 128, NQKV / 128), 256, 0, stream>>>(
      xbf, wqkvT, bqkv, nullptr, Qb, Kb, Vtb);

  attn_k<<<1024, 256, 0, stream>>>(Qb, Kb, Vtb, AO);

  gemm128<1><<<dim3(M_ / 128, C_ / 128), 256, 0, stream>>>(
      AO, wprojT, bproj, out, nullptr, nullptr, nullptr);
}

// Round 4
// 184.223 us; speedup vs baseline: 1.3258x; 1.3258x over previous
//
#include <hip/hip_runtime.h>

#define B_    2
#define T_    2048
#define C_    1024
#define H_    16
#define DH_   64
#define M_    (B_ * T_)        // 4096 tokens
#define NQKV  (3 * C_)         // 3072

typedef __bf16 bf16;
typedef __bf16 bf16x4 __attribute__((ext_vector_type(4)));
typedef __bf16 bf16x8 __attribute__((ext_vector_type(8)));
typedef float  f32x4  __attribute__((ext_vector_type(4)));

// async global->LDS, 16B per lane (global_load_lds_dwordx4).
// LDS dest must be wave-uniform base + lane*16 (no per-lane scatter).
__device__ __forceinline__ void async16(const void* g, void* l) {
  __builtin_amdgcn_global_load_lds(
      (const __attribute__((address_space(1))) void*)g,
      (__attribute__((address_space(3))) void*)l, 16, 0, 0);
}

// ---------------------------------------------------------------- converts
__global__ __launch_bounds__(256) void cvt_bf16_k(const float* __restrict__ in,
                                                  bf16* __restrict__ out) {
  const int i = (blockIdx.x * 256 + threadIdx.x) * 4;
  float4 v = *(const float4*)(in + i);
  bf16x4 o;
  o[0] = (bf16)v.x; o[1] = (bf16)v.y; o[2] = (bf16)v.z; o[3] = (bf16)v.w;
  *(bf16x4*)(out + i) = o;
}

// in: fp32 [R x C] row-major; out: bf16 [C x R] (i.e. transposed), both coalesced
__global__ __launch_bounds__(256) void transpose_cvt(const float* __restrict__ in,
                                                     bf16* __restrict__ out,
                                                     int R, int C) {
  __shared__ float tile[32][33];
  const int c0 = blockIdx.x * 32, r0 = blockIdx.y * 32;
  const int tx = threadIdx.x, ty = threadIdx.y;
#pragma unroll
  for (int j = 0; j < 4; j++)
    tile[ty + j * 8][tx] = in[(size_t)(r0 + ty + j * 8) * C + c0 + tx];
  __syncthreads();
#pragma unroll
  for (int j = 0; j < 4; j++)
    out[(size_t)(c0 + ty + j * 8) * R + r0 + tx] = (bf16)tile[tx][ty + j * 8];
}

// ---------------------------------------------------------------- GEMM (r2 structure)
// C[M,N] = A[M,K=1024] * Bt[N,K]^T (+bias). 128x128 tile, BK=32, 4 waves.
// Single-buffer staging (6 blocks/CU; cross-block overlap does the hiding —
// explicit dbuf regressed in r3 by cutting occupancy).
// LDS column-groups XOR-swizzled by (row>>1)&3 (kills 8-way b128 conflict).
template <int EPI>
__global__ __launch_bounds__(256) void gemm128(
    const bf16* __restrict__ A, const bf16* __restrict__ Bt,
    const float* __restrict__ bias, float* __restrict__ outF,
    bf16* __restrict__ qb, bf16* __restrict__ kb, bf16* __restrict__ vtb) {
  constexpr int K = 1024;
  __shared__ alignas(16) bf16 As[128 * 32];
  __shared__ alignas(16) bf16 Bs[128 * 32];
  const int tid = threadIdx.x;
  const int lane = tid & 63, wv = tid >> 6;
  const int l15 = lane & 15, quad = lane >> 4;
  const int wm = (wv >> 1) * 64, wn = (wv & 1) * 64;
  const int m0 = blockIdx.x * 128, n0 = blockIdx.y * 128;

  f32x4 acc[4][4] = {};

  const int arow = tid >> 2;                       // 0..63 (and +64)
  const int ag = (tid & 3) ^ ((arow >> 1) & 3);    // swizzled col group
  const bf16* ga = A + (size_t)(m0 + arow) * K + ag * 8;
  const bf16* gb = Bt + (size_t)(n0 + arow) * K + ag * 8;
  bf16* lA = As + tid * 8;
  bf16* lB = Bs + tid * 8;
  const int rg = (quad ^ ((l15 >> 1) & 3)) * 8;    // read-side swizzled group

  for (int k0 = 0; k0 < K; k0 += 32) {
    async16(ga + k0, lA);
    async16(ga + k0 + (size_t)64 * K, lA + 2048);
    async16(gb + k0, lB);
    async16(gb + k0 + (size_t)64 * K, lB + 2048);
    __syncthreads();
    bf16x8 af[4], bfr[4];
#pragma unroll
    for (int i = 0; i < 4; i++)
      af[i] = *(const bf16x8*)(As + (wm + i * 16 + l15) * 32 + rg);
#pragma unroll
    for (int j = 0; j < 4; j++)
      bfr[j] = *(const bf16x8*)(Bs + (wn + j * 16 + l15) * 32 + rg);
#pragma unroll
    for (int i = 0; i < 4; i++)
#pragma unroll
      for (int j = 0; j < 4; j++)
        acc[i][j] = __builtin_amdgcn_mfma_f32_16x16x32_bf16(af[i], bfr[j],
                                                            acc[i][j], 0, 0, 0);
    __syncthreads();
  }

  // epilogue: C/D layout col=lane&15, row=quad*4+reg
#pragma unroll
  for (int i = 0; i < 4; i++) {
#pragma unroll
    for (int j = 0; j < 4; j++) {
      const int gcol = n0 + wn + j * 16 + l15;
      const float bv = bias[gcol];
#pragma unroll
      for (int r = 0; r < 4; r++) {
        const int grow = m0 + wm + i * 16 + quad * 4 + r;
        float v = acc[i][j][r] + bv;
        if constexpr (EPI == 0) {
          const int which = gcol >> 10;          // 0=Q 1=K 2=V
          const int hn = gcol & 1023;
          const int h = hn >> 6, d = hn & 63;
          const int bb = grow >> 11, t = grow & 2047;
          const int head = bb * 16 + h;          // 0..31
          if (which == 0)
            qb[head * 131072 + t * 64 + d] = (bf16)(v * 0.1803368801f); // 1/8 * log2(e)
          else if (which == 1)
            kb[head * 131072 + t * 64 + d] = (bf16)v;
          else
            vtb[head * 131072 + d * 2048 + t] = (bf16)v;
        } else {
          outF[(size_t)grow * 1024 + gcol] = v;
        }
      }
    }
  }
}

// ---------------------------------------------------------------- flash attention
// 256 blocks x 512 threads (8 waves): exactly 1 block/CU, each block processes
// TWO q-tiles of 128 (qJ = x and 15-x) sequentially -> uniform 34 tile-iters
// per CU (no load-imbalance tail). Head pinned to blockIdx&7 so (assuming
// round-robin XCD dispatch) each XCD's L2 holds only 4 heads' K/V (2 MB).
// Swapped-operand MFMAs: St = K*Q^T, O^T = V*P^T -- each lane owns ONE q row:
// softmax = 15 local VALU + 2 shfls; P staged as 4x ds_write_b64 per lane.
// K/V double-buffered (LDS can't hurt occupancy at 1 block/CU); K-frags are
// read BEFORE the prefetch issue so no vmcnt wait lands on them.
__global__ __launch_bounds__(512) void attn_k(const bf16* __restrict__ Q,
                                              const bf16* __restrict__ K,
                                              const bf16* __restrict__ Vt,
                                              bf16* __restrict__ O) {
  __shared__ alignas(16) bf16 Ks[2][64 * 64];    // [kt][d], swizzled
  __shared__ alignas(16) bf16 Vs[2][64 * 64];    // [d][kt], swizzled
  __shared__ alignas(16) bf16 Ps[8][16 * 64];    // per-wave P^T staging
  const int tid = threadIdx.x, lane = tid & 63, wv = tid >> 6;  // wv 0..7
  const int l15 = lane & 15, quad = lane >> 4;

  const int b = blockIdx.x;
  const int bh = (b & 7) | ((b >> 6) << 3);      // head: same XCD for all 8 pair-blocks
  const int xpair = (b >> 3) & 7;

  const bf16* Qb = Q + (size_t)bh * 131072;
  const bf16* Kb = K + (size_t)bh * 131072;
  const bf16* Vb = Vt + (size_t)bh * 131072;

  const int srow = tid >> 3;                     // 0..63
  const int sg = (tid & 7) ^ (srow & 7);         // staging swizzle (global side)
  const bf16* gk = Kb + srow * 64 + sg * 8;
  const bf16* gv = Vb + srow * 2048 + sg * 8;
  const int swz = l15 & 7;                       // read-side swizzle key
  bf16* Pw = Ps[wv];
  const int bb = bh >> 4, h = bh & 15;

  for (int t = 0; t < 2; ++t) {
    const int qJ = t ? (15 - xpair) : xpair;
    const int q0 = qJ * 128;
    const int nIter = 2 * qJ + 2;
    const int q = q0 + wv * 16 + l15;            // this lane's q row

    // Q B-frags: B[n=q][k=d] -- lane l15 = q, quad holds d-chunk
    bf16x8 aq0 = *(const bf16x8*)(Qb + q * 64 + quad * 8);
    bf16x8 aq1 = *(const bf16x8*)(Qb + q * 64 + 32 + quad * 8);

    f32x4 o[4] = {};                             // O^T[d-block][q]: d = nf*16+quad*4+r
    float m = -3.0e38f, lsum = 0.f;

    // stage kt-tile 0 into buffer 0 (512 thr * 16B = 8KB = whole tile, 1 call)
    async16(gk, &Ks[0][tid * 8]);
    async16(gv, &Vs[0][tid * 8]);

    for (int it = 0; it < nIter; ++it) {
      __syncthreads();                           // drains L(it)
      const bf16* Kc = Ks[it & 1];
      const bf16* Vc = Vs[it & 1];

      // K A-frags first (before prefetch issue): A[m=kt][k=d]
      bf16x8 kf[2][4];
#pragma unroll
      for (int kc = 0; kc < 2; kc++)
#pragma unroll
        for (int nf = 0; nf < 4; nf++)
          kf[kc][nf] = *(const bf16x8*)(Kc + (nf * 16 + l15) * 64 +
                                        (((kc * 4 + quad) ^ swz) * 8));

      if (it + 1 < nIter) {                      // prefetch L(it+1), other buffer
        const int kt1 = (it + 1) * 64;
        const int nb = (it + 1) & 1;
        async16(gk + kt1 * 64, &Ks[nb][tid * 8]);
        async16(gv + kt1, &Vs[nb][tid * 8]);
      }

      // St = K Q^T: D[m=kt-block][n=q], s[nf][r] = S[kt=it*64+nf*16+quad*4+r][q]
      f32x4 s[4] = {};
#pragma unroll
      for (int kc = 0; kc < 2; kc++) {
        bf16x8 a = kc ? aq1 : aq0;
#pragma unroll
        for (int nf = 0; nf < 4; nf++)
          s[nf] = __builtin_amdgcn_mfma_f32_16x16x32_bf16(kf[kc][nf], a, s[nf], 0, 0, 0);
      }

      if (it >= nIter - 2) {                     // only the 2 diag-overlap tiles
#pragma unroll
        for (int nf = 0; nf < 4; nf++)
#pragma unroll
          for (int r = 0; r < 4; r++) {
            const int kt = it * 64 + nf * 16 + quad * 4 + r;
            if (kt > q) s[nf][r] = -3.0e38f;
          }
      }

      // per-lane online softmax for its single q row (16 local kt + cross-quad)
      float mx = s[0][0];
#pragma unroll
      for (int nf = 0; nf < 4; nf++)
#pragma unroll
        for (int r = 0; r < 4; r++) mx = fmaxf(mx, s[nf][r]);
      mx = fmaxf(mx, __shfl_xor(mx, 16));
      mx = fmaxf(mx, __shfl_xor(mx, 32));
      const float mnew = fmaxf(m, mx);
      const float alpha = __builtin_amdgcn_exp2f(m - mnew);
      m = mnew;
      float ts = 0.f;
      bf16x4 p4[4];
#pragma unroll
      for (int nf = 0; nf < 4; nf++)
#pragma unroll
        for (int r = 0; r < 4; r++) {
          const float pv = __builtin_amdgcn_exp2f(s[nf][r] - mnew);
          ts += pv;
          p4[nf][r] = (bf16)pv;
        }
      ts += __shfl_xor(ts, 16);
      ts += __shfl_xor(ts, 32);
      lsum = lsum * alpha + ts;
#pragma unroll
      for (int nf = 0; nf < 4; nf++)
#pragma unroll
        for (int r = 0; r < 4; r++) o[nf][r] *= alpha;

      // P^T stage: row = q (l15), 4x b64, 16B-group G = kt>>3 xor-swizzled
#pragma unroll
      for (int nf = 0; nf < 4; nf++)
        *(bf16x4*)(Pw + l15 * 64 + ((((nf << 1) | (quad >> 1)) ^ swz) << 3) +
                   ((quad & 1) << 2)) = p4[nf];

      // P B-frags: B[n=q][k=kt-chunk]  (same-wave DS ordering; no barrier)
      bf16x8 pb0 = *(const bf16x8*)(Pw + l15 * 64 + ((quad ^ swz) << 3));
      bf16x8 pb1 = *(const bf16x8*)(Pw + l15 * 64 + (((4 + quad) ^ swz) << 3));

      // O^T += V P^T: A[m=d][k=kt] from Vs, B = pb
#pragma unroll
      for (int kc = 0; kc < 2; kc++) {
        bf16x8 pb = kc ? pb1 : pb0;
#pragma unroll
        for (int nf = 0; nf < 4; nf++) {
          bf16x8 vf = *(const bf16x8*)(Vc + (nf * 16 + l15) * 64 +
                                       (((kc * 4 + quad) ^ swz) * 8));
          o[nf] = __builtin_amdgcn_mfma_f32_16x16x32_bf16(vf, pb, o[nf], 0, 0, 0);
        }
      }
    }

    // epilogue: lane owns q; d = nf*16+quad*4+r -> 4x 8B stores
    const float inv = 1.0f / lsum;
#pragma unroll
    for (int nf = 0; nf < 4; nf++) {
      bf16x4 ov;
#pragma unroll
      for (int r = 0; r < 4; r++) ov[r] = (bf16)(o[nf][r] * inv);
      *(bf16x4*)(O + (size_t)(bb * 2048 + q) * 1024 + h * 64 + nf * 16 + quad * 4) = ov;
    }
  }
}

// ---------------------------------------------------------------- launch
extern "C" void kernel_launch(void* const* d_in, const int* in_sizes, int n_in,
                              void* d_out, int out_size, void* d_ws, size_t ws_size,
                              hipStream_t stream) {
  const float* x     = (const float*)d_in[0];
  const float* Wqkv  = (const float*)d_in[1];
  const float* bqkv  = (const float*)d_in[2];
  const float* Wproj = (const float*)d_in[3];
  const float* bproj = (const float*)d_in[4];
  float* out = (float*)d_out;

  char* p = (char*)d_ws;
  bf16* xbf    = (bf16*)p; p += (size_t)M_ * C_ * 2;     // 8 MB
  bf16* wqkvT  = (bf16*)p; p += (size_t)NQKV * C_ * 2;   // 6 MB
  bf16* wprojT = (bf16*)p; p += (size_t)C_ * C_ * 2;     // 2 MB
  bf16* Qb     = (bf16*)p; p += (size_t)M_ * C_ * 2;     // 8 MB
  bf16* Kb     = (bf16*)p; p += (size_t)M_ * C_ * 2;     // 8 MB
  bf16* Vtb    = (bf16*)p; p += (size_t)M_ * C_ * 2;     // 8 MB
  bf16* AO     = (bf16*)p;                               // 8 MB (total 48 MB)

  cvt_bf16_k<<<M_ * C_ / 1024, 256, 0, stream>>>(x, xbf);
  transpose_cvt<<<dim3(NQKV / 32, C_ / 32), dim3(32, 8), 0, stream>>>(Wqkv, wqkvT, C_, NQKV);
  transpose_cvt<<<dim3(C_ / 32, C_ / 32), dim3(32, 8), 0, stream>>>(Wproj, wprojT, C_, C_);

  gemm128<0><<<dim3(M_ / 128, NQKV / 128), 256, 0, stream>>>(
      xbf, wqkvT, bqkv, nullptr, Qb, Kb, Vtb);

  attn_k<<<256, 512, 0, stream>>>(Qb, Kb, Vtb, AO);

  gemm128<1><<<dim3(M_ / 128, C_ / 128), 256, 0, stream>>>(
      AO, wprojT, bproj, out, nullptr, nullptr, nullptr);
}

// Round 5
// 177.548 us; speedup vs baseline: 1.3757x; 1.0376x over previous
//
#include <hip/hip_runtime.h>

#define B_    2
#define T_    2048
#define C_    1024
#define H_    16
#define DH_   64
#define M_    (B_ * T_)        // 4096 tokens
#define NQKV  (3 * C_)         // 3072

typedef __bf16 bf16;
typedef __bf16 bf16x4 __attribute__((ext_vector_type(4)));
typedef __bf16 bf16x8 __attribute__((ext_vector_type(8)));
typedef float  f32x4  __attribute__((ext_vector_type(4)));

// async global->LDS, 16B per lane (global_load_lds_dwordx4).
// LDS dest must be wave-uniform base + lane*16 (no per-lane scatter).
__device__ __forceinline__ void async16(const void* g, void* l) {
  __builtin_amdgcn_global_load_lds(
      (const __attribute__((address_space(1))) void*)g,
      (__attribute__((address_space(3))) void*)l, 16, 0, 0);
}

// ---------------------------------------------------------------- converts
__global__ __launch_bounds__(256) void cvt_bf16_k(const float* __restrict__ in,
                                                  bf16* __restrict__ out) {
  const int i = (blockIdx.x * 256 + threadIdx.x) * 4;
  float4 v = *(const float4*)(in + i);
  bf16x4 o;
  o[0] = (bf16)v.x; o[1] = (bf16)v.y; o[2] = (bf16)v.z; o[3] = (bf16)v.w;
  *(bf16x4*)(out + i) = o;
}

// in: fp32 [R x C] row-major; out: bf16 [C x R] (i.e. transposed), both coalesced
__global__ __launch_bounds__(256) void transpose_cvt(const float* __restrict__ in,
                                                     bf16* __restrict__ out,
                                                     int R, int C) {
  __shared__ float tile[32][33];
  const int c0 = blockIdx.x * 32, r0 = blockIdx.y * 32;
  const int tx = threadIdx.x, ty = threadIdx.y;
#pragma unroll
  for (int j = 0; j < 4; j++)
    tile[ty + j * 8][tx] = in[(size_t)(r0 + ty + j * 8) * C + c0 + tx];
  __syncthreads();
#pragma unroll
  for (int j = 0; j < 4; j++)
    out[(size_t)(c0 + ty + j * 8) * R + r0 + tx] = (bf16)tile[tx][ty + j * 8];
}

// ---------------------------------------------------------------- GEMM (r2 structure)
// C[M,N] = A[M,K=1024] * Bt[N,K]^T (+bias). 128x128 tile, BK=32, 4 waves.
// Single-buffer staging (cross-block overlap does the hiding — explicit dbuf
// regressed in r3). LDS groups XOR-swizzled by (row>>1)&3.
template <int EPI>
__global__ __launch_bounds__(256) void gemm128(
    const bf16* __restrict__ A, const bf16* __restrict__ Bt,
    const float* __restrict__ bias, float* __restrict__ outF,
    bf16* __restrict__ qb, bf16* __restrict__ kb, bf16* __restrict__ vtb) {
  constexpr int K = 1024;
  __shared__ alignas(16) bf16 As[128 * 32];
  __shared__ alignas(16) bf16 Bs[128 * 32];
  const int tid = threadIdx.x;
  const int lane = tid & 63, wv = tid >> 6;
  const int l15 = lane & 15, quad = lane >> 4;
  const int wm = (wv >> 1) * 64, wn = (wv & 1) * 64;
  const int m0 = blockIdx.x * 128, n0 = blockIdx.y * 128;

  f32x4 acc[4][4] = {};

  const int arow = tid >> 2;                       // 0..63 (and +64)
  const int ag = (tid & 3) ^ ((arow >> 1) & 3);    // swizzled col group
  const bf16* ga = A + (size_t)(m0 + arow) * K + ag * 8;
  const bf16* gb = Bt + (size_t)(n0 + arow) * K + ag * 8;
  bf16* lA = As + tid * 8;
  bf16* lB = Bs + tid * 8;
  const int rg = (quad ^ ((l15 >> 1) & 3)) * 8;    // read-side swizzled group

  for (int k0 = 0; k0 < K; k0 += 32) {
    async16(ga + k0, lA);
    async16(ga + k0 + (size_t)64 * K, lA + 2048);
    async16(gb + k0, lB);
    async16(gb + k0 + (size_t)64 * K, lB + 2048);
    __syncthreads();
    bf16x8 af[4], bfr[4];
#pragma unroll
    for (int i = 0; i < 4; i++)
      af[i] = *(const bf16x8*)(As + (wm + i * 16 + l15) * 32 + rg);
#pragma unroll
    for (int j = 0; j < 4; j++)
      bfr[j] = *(const bf16x8*)(Bs + (wn + j * 16 + l15) * 32 + rg);
#pragma unroll
    for (int i = 0; i < 4; i++)
#pragma unroll
      for (int j = 0; j < 4; j++)
        acc[i][j] = __builtin_amdgcn_mfma_f32_16x16x32_bf16(af[i], bfr[j],
                                                            acc[i][j], 0, 0, 0);
    __syncthreads();
  }

  // epilogue: C/D layout col=lane&15, row=quad*4+reg
#pragma unroll
  for (int i = 0; i < 4; i++) {
#pragma unroll
    for (int j = 0; j < 4; j++) {
      const int gcol = n0 + wn + j * 16 + l15;
      const float bv = bias[gcol];
#pragma unroll
      for (int r = 0; r < 4; r++) {
        const int grow = m0 + wm + i * 16 + quad * 4 + r;
        float v = acc[i][j][r] + bv;
        if constexpr (EPI == 0) {
          const int which = gcol >> 10;          // 0=Q 1=K 2=V
          const int hn = gcol & 1023;
          const int h = hn >> 6, d = hn & 63;
          const int bb = grow >> 11, t = grow & 2047;
          const int head = bb * 16 + h;          // 0..31
          if (which == 0)
            qb[head * 131072 + t * 64 + d] = (bf16)(v * 0.1803368801f); // 1/8 * log2(e)
          else if (which == 1)
            kb[head * 131072 + t * 64 + d] = (bf16)v;
          else
            vtb[head * 131072 + d * 2048 + t] = (bf16)v;
        } else {
          outF[(size_t)grow * 1024 + gcol] = v;
        }
      }
    }
  }
}

// ---------------------------------------------------------------- flash attention
// 256 blocks x 512 threads (8 waves), 1 block/CU; each block does q-tiles
// qJ = x and 15-x sequentially -> uniform 17 kt-tile iters per CU.
// kt-tile = 128 (was 64): halves the iteration count so the per-iter serial
// dependency chain (kf load -> S -> softmax -> P LDS round-trip -> PV), which
// r4 counters showed costs ~2000cy/iter beyond issue work, is paid half as
// often. Head pinned to blockIdx&7 for XCD L2 locality (r4: FETCH 63->12MB).
// Swapped-operand MFMAs: St = K*Q^T, O^T = V*P^T; each lane owns ONE q row.
__global__ __launch_bounds__(512, 2) void attn_k(const bf16* __restrict__ Q,
                                                 const bf16* __restrict__ K,
                                                 const bf16* __restrict__ Vt,
                                                 bf16* __restrict__ O) {
  __shared__ alignas(16) bf16 Ks[2][128 * 64];   // [kt][d], 8-group swizzle
  __shared__ alignas(16) bf16 Vs[2][64 * 128];   // [d][kt], 16-group swizzle
  __shared__ alignas(16) bf16 Ps[8][16 * 128];   // per-wave P^T, 16-group swizzle
  const int tid = threadIdx.x, lane = tid & 63, wv = tid >> 6;  // wv 0..7
  const int l15 = lane & 15, quad = lane >> 4;

  const int b = blockIdx.x;
  const int bh = (b & 7) | ((b >> 6) << 3);      // head: same XCD across pair-blocks
  const int xpair = (b >> 3) & 7;

  const bf16* Qb = Q + (size_t)bh * 131072;
  const bf16* Kb = K + (size_t)bh * 131072;
  const bf16* Vb = Vt + (size_t)bh * 131072;

  // staging addresses. K tile: 128 rows x 128B, 2 calls of 64 rows.
  const int krow = tid >> 3;                     // 0..63
  const int kg = (tid & 7) ^ (krow & 7);
  const bf16* gk = Kb + krow * 64 + kg * 8;
  // V tile: 64 rows x 256B (16 groups), 2 calls of 32 rows.
  const int vrow = tid >> 4;                     // 0..31
  const int vg = (tid & 15) ^ (vrow & 15);
  const bf16* gv = Vb + vrow * 2048 + vg * 8;

  const int swz7 = l15 & 7;                      // K read swizzle key
  bf16* Pw = Ps[wv];
  const int bb = bh >> 4, h = bh & 15;

  for (int t = 0; t < 2; ++t) {
    const int qJ = t ? (15 - xpair) : xpair;
    const int q0 = qJ * 128;
    const int nIter = qJ + 1;
    const int q = q0 + wv * 16 + l15;            // this lane's q row

    // Q B-frags: B[n=q][k=d]
    bf16x8 aq0 = *(const bf16x8*)(Qb + q * 64 + quad * 8);
    bf16x8 aq1 = *(const bf16x8*)(Qb + q * 64 + 32 + quad * 8);

    f32x4 o[4] = {};                             // O^T: d = nf*16+quad*4+r
    float m = -3.0e38f, lsum = 0.f;

    __syncthreads();  // Ks/Vs from previous q-tile no longer read (parity varies)
    async16(gk, &Ks[0][tid * 8]);
    async16(gk + 64 * 64, &Ks[0][tid * 8 + 4096]);
    async16(gv, &Vs[0][tid * 8]);
    async16(gv + 32 * 2048, &Vs[0][tid * 8 + 4096]);

    for (int it = 0; it < nIter; ++it) {
      __syncthreads();                           // drains L(it)
      const bf16* Kc = Ks[it & 1];
      const bf16* Vc = Vs[it & 1];

      // K A-frags first (before prefetch issue): A[m=kt 0..127][k=d]
      bf16x8 kf[2][8];
#pragma unroll
      for (int kc = 0; kc < 2; kc++)
#pragma unroll
        for (int nf = 0; nf < 8; nf++)
          kf[kc][nf] = *(const bf16x8*)(Kc + (nf * 16 + l15) * 64 +
                                        (((kc * 4 + quad) ^ swz7) << 3));

      if (it + 1 < nIter) {                      // prefetch L(it+1), other buffer
        const int kt1 = (it + 1) * 128;
        const int nb = (it + 1) & 1;
        async16(gk + kt1 * 64, &Ks[nb][tid * 8]);
        async16(gk + kt1 * 64 + 64 * 64, &Ks[nb][tid * 8 + 4096]);
        async16(gv + kt1, &Vs[nb][tid * 8]);
        async16(gv + kt1 + 32 * 2048, &Vs[nb][tid * 8 + 4096]);
      }

      // St = K Q^T: s[nf][r] = S[kt = it*128 + nf*16+quad*4+r][q]
      f32x4 s[8] = {};
#pragma unroll
      for (int kc = 0; kc < 2; kc++) {
        bf16x8 a = kc ? aq1 : aq0;
#pragma unroll
        for (int nf = 0; nf < 8; nf++)
          s[nf] = __builtin_amdgcn_mfma_f32_16x16x32_bf16(kf[kc][nf], a, s[nf], 0, 0, 0);
      }

      if (it == nIter - 1) {                     // only the diagonal tile
#pragma unroll
        for (int nf = 0; nf < 8; nf++)
#pragma unroll
          for (int r = 0; r < 4; r++) {
            const int kt = it * 128 + nf * 16 + quad * 4 + r;
            if (kt > q) s[nf][r] = -3.0e38f;
          }
      }

      // per-lane online softmax over its 32 kt values + cross-quad combine
      float mx = s[0][0];
#pragma unroll
      for (int nf = 0; nf < 8; nf++)
#pragma unroll
        for (int r = 0; r < 4; r++) mx = fmaxf(mx, s[nf][r]);
      mx = fmaxf(mx, __shfl_xor(mx, 16));
      mx = fmaxf(mx, __shfl_xor(mx, 32));
      const float mnew = fmaxf(m, mx);
      const float alpha = __builtin_amdgcn_exp2f(m - mnew);
      m = mnew;
      float ts = 0.f;
      bf16x4 p4[8];
#pragma unroll
      for (int nf = 0; nf < 8; nf++)
#pragma unroll
        for (int r = 0; r < 4; r++) {
          const float pv = __builtin_amdgcn_exp2f(s[nf][r] - mnew);
          ts += pv;
          p4[nf][r] = (bf16)pv;
        }
      ts += __shfl_xor(ts, 16);
      ts += __shfl_xor(ts, 32);
      lsum = lsum * alpha + ts;
#pragma unroll
      for (int nf = 0; nf < 4; nf++)
#pragma unroll
        for (int r = 0; r < 4; r++) o[nf][r] *= alpha;

      // P^T stage: row = q (l15), 8x b64; group G = (nf*2 + quad>>1) ^ l15
#pragma unroll
      for (int nf = 0; nf < 8; nf++)
        *(bf16x4*)(Pw + l15 * 128 + ((((nf << 1) | (quad >> 1)) ^ l15) << 3) +
                   ((quad & 1) << 2)) = p4[nf];

      // P B-frags: B[n=q][k=kt-chunk]  (same-wave DS ordering; no barrier)
      bf16x8 pb[4];
#pragma unroll
      for (int kc = 0; kc < 4; kc++)
        pb[kc] = *(const bf16x8*)(Pw + l15 * 128 + (((kc * 4 + quad) ^ l15) << 3));

      // O^T += V P^T: A[m=d][k=kt] from Vs
#pragma unroll
      for (int kc = 0; kc < 4; kc++)
#pragma unroll
        for (int nf = 0; nf < 4; nf++) {
          bf16x8 vf = *(const bf16x8*)(Vc + (nf * 16 + l15) * 128 +
                                       (((kc * 4 + quad) ^ l15) << 3));
          o[nf] = __builtin_amdgcn_mfma_f32_16x16x32_bf16(vf, pb[kc], o[nf], 0, 0, 0);
        }
    }

    // epilogue: lane owns q; d = nf*16+quad*4+r -> 4x 8B stores
    const float inv = 1.0f / lsum;
#pragma unroll
    for (int nf = 0; nf < 4; nf++) {
      bf16x4 ov;
#pragma unroll
      for (int r = 0; r < 4; r++) ov[r] = (bf16)(o[nf][r] * inv);
      *(bf16x4*)(O + (size_t)(bb * 2048 + q) * 1024 + h * 64 + nf * 16 + quad * 4) = ov;
    }
  }
}

// ---------------------------------------------------------------- launch
extern "C" void kernel_launch(void* const* d_in, const int* in_sizes, int n_in,
                              void* d_out, int out_size, void* d_ws, size_t ws_size,
                              hipStream_t stream) {
  const float* x     = (const float*)d_in[0];
  const float* Wqkv  = (const float*)d_in[1];
  const float* bqkv  = (const float*)d_in[2];
  const float* Wproj = (const float*)d_in[3];
  const float* bproj = (const float*)d_in[4];
  float* out = (float*)d_out;

  char* p = (char*)d_ws;
  bf16* xbf    = (bf16*)p; p += (size_t)M_ * C_ * 2;     // 8 MB
  bf16* wqkvT  = (bf16*)p; p += (size_t)NQKV * C_ * 2;   // 6 MB
  bf16* wprojT = (bf16*)p; p += (size_t)C_ * C_ * 2;     // 2 MB
  bf16* Qb     = (bf16*)p; p += (size_t)M_ * C_ * 2;     // 8 MB
  bf16* Kb     = (bf16*)p; p += (size_t)M_ * C_ * 2;     // 8 MB
  bf16* Vtb    = (bf16*)p; p += (size_t)M_ * C_ * 2;     // 8 MB
  bf16* AO     = (bf16*)p;                               // 8 MB (total 48 MB)

  cvt_bf16_k<<<M_ * C_ / 1024, 256, 0, stream>>>(x, xbf);
  transpose_cvt<<<dim3(NQKV / 32, C_ / 32), dim3(32, 8), 0, stream>>>(Wqkv, wqkvT, C_, NQKV);
  transpose_cvt<<<dim3(C_ / 32, C_ / 32), dim3(32, 8), 0, stream>>>(Wproj, wprojT, C_, C_);

  gemm128<0><<<dim3(M_ / 128, NQKV / 128), 256, 0, stream>>>(
      xbf, wqkvT, bqkv, nullptr, Qb, Kb, Vtb);

  attn_k<<<256, 512, 0, stream>>>(Qb, Kb, Vtb, AO);

  gemm128<1><<<dim3(M_ / 128, C_ / 128), 256, 0, stream>>>(
      AO, wprojT, bproj, out, nullptr, nullptr, nullptr);
}

// Round 6
// 172.990 us; speedup vs baseline: 1.4119x; 1.0263x over previous
//
#include <hip/hip_runtime.h>

#define B_    2
#define T_    2048
#define C_    1024
#define H_    16
#define DH_   64
#define M_    (B_ * T_)        // 4096 tokens
#define NQKV  (3 * C_)         // 3072

typedef __bf16 bf16;
typedef __bf16 bf16x4 __attribute__((ext_vector_type(4)));
typedef __bf16 bf16x8 __attribute__((ext_vector_type(8)));
typedef float  f32x4  __attribute__((ext_vector_type(4)));

// async global->LDS, 16B per lane (global_load_lds_dwordx4).
// LDS dest must be wave-uniform base + lane*16 (no per-lane scatter).
__device__ __forceinline__ void async16(const void* g, void* l) {
  __builtin_amdgcn_global_load_lds(
      (const __attribute__((address_space(1))) void*)g,
      (__attribute__((address_space(3))) void*)l, 16, 0, 0);
}

// ---------------------------------------------------------------- converts
__global__ __launch_bounds__(256) void cvt_bf16_k(const float* __restrict__ in,
                                                  bf16* __restrict__ out) {
  const int i = (blockIdx.x * 256 + threadIdx.x) * 4;
  float4 v = *(const float4*)(in + i);
  bf16x4 o;
  o[0] = (bf16)v.x; o[1] = (bf16)v.y; o[2] = (bf16)v.z; o[3] = (bf16)v.w;
  *(bf16x4*)(out + i) = o;
}

// in: fp32 [R x C] row-major; out: bf16 [C x R] (i.e. transposed), both coalesced
__global__ __launch_bounds__(256) void transpose_cvt(const float* __restrict__ in,
                                                     bf16* __restrict__ out,
                                                     int R, int C) {
  __shared__ float tile[32][33];
  const int c0 = blockIdx.x * 32, r0 = blockIdx.y * 32;
  const int tx = threadIdx.x, ty = threadIdx.y;
#pragma unroll
  for (int j = 0; j < 4; j++)
    tile[ty + j * 8][tx] = in[(size_t)(r0 + ty + j * 8) * C + c0 + tx];
  __syncthreads();
#pragma unroll
  for (int j = 0; j < 4; j++)
    out[(size_t)(c0 + ty + j * 8) * R + r0 + tx] = (bf16)tile[tx][ty + j * 8];
}

// ---------------------------------------------------------------- GEMM
// C[M,N] = A[M,K=1024] * Bt[N,K]^T (+bias). Tile BM x 128, BK=64, 4 waves.
// BK=64 halves the barrier count vs r5 (the m97 stall is per-barrier vmcnt(0)
// drain). LDS rows are 128B; groups XOR-swizzled by row&7 (2-way on read =
// free, attn-verified). Single-buffered: cross-block overlap does the hiding
// (explicit dbuf regressed in r3 by cutting occupancy).
// BM=128 for QKV (grid 3/CU); BM=64 for proj (grid 512 = 2 blocks/CU -- r5
// showed 1 block/CU left the k-loop stalls fully exposed, ~36us for 8.6GF).
// EPI 0: scatter Q (pre-scaled by 0.125*log2e), K [B,H,T,dh], V^T [B,H,dh,T].
// EPI 1: fp32 out[M,1024] + bias.
template <int EPI, int BM>
__global__ __launch_bounds__(256) void gemm_k(
    const bf16* __restrict__ A, const bf16* __restrict__ Bt,
    const float* __restrict__ bias, float* __restrict__ outF,
    bf16* __restrict__ qb, bf16* __restrict__ kb, bf16* __restrict__ vtb) {
  constexpr int K = 1024;
  constexpr int MI = BM / 32;                    // m-frags per wave
  __shared__ alignas(16) bf16 As[BM * 64];
  __shared__ alignas(16) bf16 Bs[128 * 64];
  const int tid = threadIdx.x;
  const int lane = tid & 63, wv = tid >> 6;
  const int l15 = lane & 15, quad = lane >> 4;
  const int wm = (wv >> 1) * (BM / 2), wn = (wv & 1) * 64;
  const int m0 = blockIdx.x * BM, n0 = blockIdx.y * 128;

  f32x4 acc[MI][4] = {};

  // staging: 16B per lane; LDS row = 128B; logical col-group = phys ^ (row&7)
  const int srow = tid >> 3;                     // 0..31 (+32c per call)
  const int sgb = ((tid & 7) ^ (srow & 7)) * 8;
  const bf16* ga = A + (size_t)(m0 + srow) * K + sgb;
  const bf16* gb = Bt + (size_t)(n0 + srow) * K + sgb;
  const int swz = l15 & 7;                       // read-side swizzle key

  for (int it = 0; it < K / 64; ++it) {
    const int k0 = it * 64;
#pragma unroll
    for (int c = 0; c < BM / 32; c++)            // A: BM rows, 32/call
      async16(ga + k0 + (size_t)(c * 32) * K, As + tid * 8 + c * 2048);
#pragma unroll
    for (int c = 0; c < 4; c++)                  // B: 128 rows
      async16(gb + k0 + (size_t)(c * 32) * K, Bs + tid * 8 + c * 2048);
    __syncthreads();
    bf16x8 af[2][MI], bfr[2][4];
#pragma unroll
    for (int kb = 0; kb < 2; kb++) {
#pragma unroll
      for (int i = 0; i < MI; i++)
        af[kb][i] = *(const bf16x8*)(As + (wm + i * 16 + l15) * 64 +
                                     (((kb * 4 + quad) ^ swz) << 3));
#pragma unroll
      for (int j = 0; j < 4; j++)
        bfr[kb][j] = *(const bf16x8*)(Bs + (wn + j * 16 + l15) * 64 +
                                      (((kb * 4 + quad) ^ swz) << 3));
    }
#pragma unroll
    for (int kb = 0; kb < 2; kb++)
#pragma unroll
      for (int i = 0; i < MI; i++)
#pragma unroll
        for (int j = 0; j < 4; j++)
          acc[i][j] = __builtin_amdgcn_mfma_f32_16x16x32_bf16(
              af[kb][i], bfr[kb][j], acc[i][j], 0, 0, 0);
    __syncthreads();
  }

  // epilogue: C/D layout col=lane&15, row=quad*4+reg
#pragma unroll
  for (int i = 0; i < MI; i++) {
#pragma unroll
    for (int j = 0; j < 4; j++) {
      const int gcol = n0 + wn + j * 16 + l15;
      const float bv = bias[gcol];
#pragma unroll
      for (int r = 0; r < 4; r++) {
        const int grow = m0 + wm + i * 16 + quad * 4 + r;
        float v = acc[i][j][r] + bv;
        if constexpr (EPI == 0) {
          const int which = gcol >> 10;          // 0=Q 1=K 2=V
          const int hn = gcol & 1023;
          const int h = hn >> 6, d = hn & 63;
          const int bb = grow >> 11, t = grow & 2047;
          const int head = bb * 16 + h;          // 0..31
          if (which == 0)
            qb[head * 131072 + t * 64 + d] = (bf16)(v * 0.1803368801f); // 1/8 * log2(e)
          else if (which == 1)
            kb[head * 131072 + t * 64 + d] = (bf16)v;
          else
            vtb[head * 131072 + d * 2048 + t] = (bf16)v;
        } else {
          outF[(size_t)grow * 1024 + gcol] = v;
        }
      }
    }
  }
}

// ---------------------------------------------------------------- flash attention
// (r5 structure, unchanged) 256 blocks x 512 threads, 1 block/CU; each block
// does q-tiles qJ = x and 15-x sequentially -> uniform 17 kt128-iters per CU.
// Head pinned to blockIdx&7 for XCD L2 locality (FETCH 63->12MB in r4).
// Swapped-operand MFMAs: St = K*Q^T, O^T = V*P^T; each lane owns ONE q row.
__global__ __launch_bounds__(512, 2) void attn_k(const bf16* __restrict__ Q,
                                                 const bf16* __restrict__ K,
                                                 const bf16* __restrict__ Vt,
                                                 bf16* __restrict__ O) {
  __shared__ alignas(16) bf16 Ks[2][128 * 64];   // [kt][d], 8-group swizzle
  __shared__ alignas(16) bf16 Vs[2][64 * 128];   // [d][kt], 16-group swizzle
  __shared__ alignas(16) bf16 Ps[8][16 * 128];   // per-wave P^T, 16-group swizzle
  const int tid = threadIdx.x, lane = tid & 63, wv = tid >> 6;  // wv 0..7
  const int l15 = lane & 15, quad = lane >> 4;

  const int b = blockIdx.x;
  const int bh = (b & 7) | ((b >> 6) << 3);      // head: same XCD across pair-blocks
  const int xpair = (b >> 3) & 7;

  const bf16* Qb = Q + (size_t)bh * 131072;
  const bf16* Kb = K + (size_t)bh * 131072;
  const bf16* Vb = Vt + (size_t)bh * 131072;

  // staging addresses. K tile: 128 rows x 128B, 2 calls of 64 rows.
  const int krow = tid >> 3;                     // 0..63
  const int kg = (tid & 7) ^ (krow & 7);
  const bf16* gk = Kb + krow * 64 + kg * 8;
  // V tile: 64 rows x 256B (16 groups), 2 calls of 32 rows.
  const int vrow = tid >> 4;                     // 0..31
  const int vg = (tid & 15) ^ (vrow & 15);
  const bf16* gv = Vb + vrow * 2048 + vg * 8;

  const int swz7 = l15 & 7;                      // K read swizzle key
  bf16* Pw = Ps[wv];
  const int bb = bh >> 4, h = bh & 15;

  for (int t = 0; t < 2; ++t) {
    const int qJ = t ? (15 - xpair) : xpair;
    const int q0 = qJ * 128;
    const int nIter = qJ + 1;
    const int q = q0 + wv * 16 + l15;            // this lane's q row

    // Q B-frags: B[n=q][k=d]
    bf16x8 aq0 = *(const bf16x8*)(Qb + q * 64 + quad * 8);
    bf16x8 aq1 = *(const bf16x8*)(Qb + q * 64 + 32 + quad * 8);

    f32x4 o[4] = {};                             // O^T: d = nf*16+quad*4+r
    float m = -3.0e38f, lsum = 0.f;

    __syncthreads();  // Ks/Vs from previous q-tile no longer read (parity varies)
    async16(gk, &Ks[0][tid * 8]);
    async16(gk + 64 * 64, &Ks[0][tid * 8 + 4096]);
    async16(gv, &Vs[0][tid * 8]);
    async16(gv + 32 * 2048, &Vs[0][tid * 8 + 4096]);

    for (int it = 0; it < nIter; ++it) {
      __syncthreads();                           // drains L(it)
      const bf16* Kc = Ks[it & 1];
      const bf16* Vc = Vs[it & 1];

      // K A-frags first (before prefetch issue): A[m=kt 0..127][k=d]
      bf16x8 kf[2][8];
#pragma unroll
      for (int kc = 0; kc < 2; kc++)
#pragma unroll
        for (int nf = 0; nf < 8; nf++)
          kf[kc][nf] = *(const bf16x8*)(Kc + (nf * 16 + l15) * 64 +
                                        (((kc * 4 + quad) ^ swz7) << 3));

      if (it + 1 < nIter) {                      // prefetch L(it+1), other buffer
        const int kt1 = (it + 1) * 128;
        const int nb = (it + 1) & 1;
        async16(gk + kt1 * 64, &Ks[nb][tid * 8]);
        async16(gk + kt1 * 64 + 64 * 64, &Ks[nb][tid * 8 + 4096]);
        async16(gv + kt1, &Vs[nb][tid * 8]);
        async16(gv + kt1 + 32 * 2048, &Vs[nb][tid * 8 + 4096]);
      }

      // St = K Q^T: s[nf][r] = S[kt = it*128 + nf*16+quad*4+r][q]
      f32x4 s[8] = {};
#pragma unroll
      for (int kc = 0; kc < 2; kc++) {
        bf16x8 a = kc ? aq1 : aq0;
#pragma unroll
        for (int nf = 0; nf < 8; nf++)
          s[nf] = __builtin_amdgcn_mfma_f32_16x16x32_bf16(kf[kc][nf], a, s[nf], 0, 0, 0);
      }

      if (it == nIter - 1) {                     // only the diagonal tile
#pragma unroll
        for (int nf = 0; nf < 8; nf++)
#pragma unroll
          for (int r = 0; r < 4; r++) {
            const int kt = it * 128 + nf * 16 + quad * 4 + r;
            if (kt > q) s[nf][r] = -3.0e38f;
          }
      }

      // per-lane online softmax over its 32 kt values + cross-quad combine
      float mx = s[0][0];
#pragma unroll
      for (int nf = 0; nf < 8; nf++)
#pragma unroll
        for (int r = 0; r < 4; r++) mx = fmaxf(mx, s[nf][r]);
      mx = fmaxf(mx, __shfl_xor(mx, 16));
      mx = fmaxf(mx, __shfl_xor(mx, 32));
      const float mnew = fmaxf(m, mx);
      const float alpha = __builtin_amdgcn_exp2f(m - mnew);
      m = mnew;
      float ts = 0.f;
      bf16x4 p4[8];
#pragma unroll
      for (int nf = 0; nf < 8; nf++)
#pragma unroll
        for (int r = 0; r < 4; r++) {
          const float pv = __builtin_amdgcn_exp2f(s[nf][r] - mnew);
          ts += pv;
          p4[nf][r] = (bf16)pv;
        }
      ts += __shfl_xor(ts, 16);
      ts += __shfl_xor(ts, 32);
      lsum = lsum * alpha + ts;
#pragma unroll
      for (int nf = 0; nf < 4; nf++)
#pragma unroll
        for (int r = 0; r < 4; r++) o[nf][r] *= alpha;

      // P^T stage: row = q (l15), 8x b64; group G = (nf*2 + quad>>1) ^ l15
#pragma unroll
      for (int nf = 0; nf < 8; nf++)
        *(bf16x4*)(Pw + l15 * 128 + ((((nf << 1) | (quad >> 1)) ^ l15) << 3) +
                   ((quad & 1) << 2)) = p4[nf];

      // P B-frags: B[n=q][k=kt-chunk]  (same-wave DS ordering; no barrier)
      bf16x8 pb[4];
#pragma unroll
      for (int kc = 0; kc < 4; kc++)
        pb[kc] = *(const bf16x8*)(Pw + l15 * 128 + (((kc * 4 + quad) ^ l15) << 3));

      // O^T += V P^T: A[m=d][k=kt] from Vs
#pragma unroll
      for (int kc = 0; kc < 4; kc++)
#pragma unroll
        for (int nf = 0; nf < 4; nf++) {
          bf16x8 vf = *(const bf16x8*)(Vc + (nf * 16 + l15) * 128 +
                                       (((kc * 4 + quad) ^ l15) << 3));
          o[nf] = __builtin_amdgcn_mfma_f32_16x16x32_bf16(vf, pb[kc], o[nf], 0, 0, 0);
        }
    }

    // epilogue: lane owns q; d = nf*16+quad*4+r -> 4x 8B stores
    const float inv = 1.0f / lsum;
#pragma unroll
    for (int nf = 0; nf < 4; nf++) {
      bf16x4 ov;
#pragma unroll
      for (int r = 0; r < 4; r++) ov[r] = (bf16)(o[nf][r] * inv);
      *(bf16x4*)(O + (size_t)(bb * 2048 + q) * 1024 + h * 64 + nf * 16 + quad * 4) = ov;
    }
  }
}

// ---------------------------------------------------------------- launch
extern "C" void kernel_launch(void* const* d_in, const int* in_sizes, int n_in,
                              void* d_out, int out_size, void* d_ws, size_t ws_size,
                              hipStream_t stream) {
  const float* x     = (const float*)d_in[0];
  const float* Wqkv  = (const float*)d_in[1];
  const float* bqkv  = (const float*)d_in[2];
  const float* Wproj = (const float*)d_in[3];
  const float* bproj = (const float*)d_in[4];
  float* out = (float*)d_out;

  char* p = (char*)d_ws;
  bf16* xbf    = (bf16*)p; p += (size_t)M_ * C_ * 2;     // 8 MB
  bf16* wqkvT  = (bf16*)p; p += (size_t)NQKV * C_ * 2;   // 6 MB
  bf16* wprojT = (bf16*)p; p += (size_t)C_ * C_ * 2;     // 2 MB
  bf16* Qb     = (bf16*)p; p += (size_t)M_ * C_ * 2;     // 8 MB
  bf16* Kb     = (bf16*)p; p += (size_t)M_ * C_ * 2;     // 8 MB
  bf16* Vtb    = (bf16*)p; p += (size_t)M_ * C_ * 2;     // 8 MB
  bf16* AO     = (bf16*)p;                               // 8 MB (total 48 MB)

  cvt_bf16_k<<<M_ * C_ / 1024, 256, 0, stream>>>(x, xbf);
  transpose_cvt<<<dim3(NQKV / 32, C_ / 32), dim3(32, 8), 0, stream>>>(Wqkv, wqkvT, C_, NQKV);
  transpose_cvt<<<dim3(C_ / 32, C_ / 32), dim3(32, 8), 0, stream>>>(Wproj, wprojT, C_, C_);

  gemm_k<0, 128><<<dim3(M_ / 128, NQKV / 128), 256, 0, stream>>>(
      xbf, wqkvT, bqkv, nullptr, Qb, Kb, Vtb);

  attn_k<<<256, 512, 0, stream>>>(Qb, Kb, Vtb, AO);

  gemm_k<1, 64><<<dim3(M_ / 64, C_ / 128), 256, 0, stream>>>(
      AO, wprojT, bproj, out, nullptr, nullptr, nullptr);
}